// Round 2
// baseline (11961.730 us; speedup 1.0000x reference)
//
#include <hip/hip_runtime.h>
#include <hip/hip_bf16.h>

#define D 256
#define NH 8
#define DH 32
#define NL 4
#define NP 4
#define DFFN 1024
#define LEN_IN 21760
#define NB 8
#define LQ 1000

typedef __hip_bfloat16 bf16;

__device__ inline float toF(float x) { return x; }
__device__ inline float toF(bf16 x) { return __bfloat162float(x); }

template <typename T> __device__ inline T fromF(float x);
template <> __device__ inline float fromF<float>(float x) { return x; }
template <> __device__ inline bf16 fromF<bf16>(float x) { return __float2bfloat16(x); }

// ---------------- elementwise add ----------------
__global__ __launch_bounds__(256) void add_ff(const float* __restrict__ a, const float* __restrict__ b,
                                              float* __restrict__ o, int n) {
    int i = blockIdx.x * 256 + threadIdx.x;
    if (i < n) o[i] = a[i] + b[i];
}

// ---------------- GEMM: C[M,N] = A[M,K] @ W[N,K]^T + bias, optional relu ----------------
template <typename TC>
__global__ __launch_bounds__(256) void gemm_kernel(const float* __restrict__ A, const float* __restrict__ W,
                                                   const float* __restrict__ bias, TC* __restrict__ C,
                                                   int M, int N, int K, int do_relu) {
    __shared__ float As[16][65];
    __shared__ float Bs[16][65];
    const int tid = threadIdx.x;
    const int m0 = blockIdx.y * 64, n0 = blockIdx.x * 64;
    const int tm = (tid >> 4) << 2;
    const int tn = (tid & 15) << 2;
    const int lr = tid >> 2;          // 0..63
    const int lc = (tid & 3) << 2;    // 0,4,8,12
    float acc[4][4] = {};
    for (int k0 = 0; k0 < K; k0 += 16) {
        const float* ap = A + (size_t)(m0 + lr) * K + (k0 + lc);
        const float* wp = W + (size_t)(n0 + lr) * K + (k0 + lc);
        float a0 = ap[0], a1 = ap[1], a2 = ap[2], a3 = ap[3];
        float b0 = wp[0], b1 = wp[1], b2 = wp[2], b3 = wp[3];
        As[lc + 0][lr] = a0; As[lc + 1][lr] = a1; As[lc + 2][lr] = a2; As[lc + 3][lr] = a3;
        Bs[lc + 0][lr] = b0; Bs[lc + 1][lr] = b1; Bs[lc + 2][lr] = b2; Bs[lc + 3][lr] = b3;
        __syncthreads();
#pragma unroll
        for (int kk = 0; kk < 16; ++kk) {
            float av[4], bv[4];
#pragma unroll
            for (int i = 0; i < 4; ++i) av[i] = As[kk][tm + i];
#pragma unroll
            for (int j = 0; j < 4; ++j) bv[j] = Bs[kk][tn + j];
#pragma unroll
            for (int i = 0; i < 4; ++i)
#pragma unroll
                for (int j = 0; j < 4; ++j) acc[i][j] += av[i] * bv[j];
        }
        __syncthreads();
    }
#pragma unroll
    for (int i = 0; i < 4; ++i) {
        int m = m0 + tm + i;
        if (m < M) {
#pragma unroll
            for (int j = 0; j < 4; ++j) {
                int nn = n0 + tn + j;
                float r = acc[i][j] + bias[nn];
                if (do_relu) r = fmaxf(r, 0.0f);
                C[(size_t)m * N + nn] = fromF<TC>(r);
            }
        }
    }
}

// ---------------- self-attention: softmax(QK^T/sqrt(DH)) V, per (n,h), 8 queries/block ----------------
__global__ __launch_bounds__(256) void attn_kernel(const float* __restrict__ q, const float* __restrict__ k,
                                                   const float* __restrict__ v, float* __restrict__ out) {
    const int q0 = blockIdx.x * 8;
    const int h = blockIdx.y;
    const int n = blockIdx.z;
    __shared__ float sc[8][1000];
    __shared__ float ks[128][33];
    __shared__ float qv[8][33];
    __shared__ float red[4];
    const int tid = threadIdx.x;

    {
        int qq = tid >> 5, d = tid & 31;
        qv[qq][d] = q[((size_t)(n * LQ + q0 + qq)) * D + h * DH + d] * 0.17677669529663687f;
    }
    __syncthreads();

    // scores
    for (int jt = 0; jt < LQ; jt += 128) {
        int cnt = min(128, LQ - jt);
        __syncthreads();
        for (int e = tid; e < cnt * 32; e += 256) {
            int row = e >> 5, col = e & 31;
            ks[row][col] = k[((size_t)(n * LQ + jt + row)) * D + h * DH + col];
        }
        __syncthreads();
        for (int idx = tid; idx < cnt * 8; idx += 256) {
            int qq = idx & 7, j = idx >> 3;
            float dot = 0.f;
#pragma unroll
            for (int d = 0; d < 32; ++d) dot += qv[qq][d] * ks[j][d];
            sc[qq][jt + j] = dot;
        }
    }
    __syncthreads();

    // softmax per row
    for (int qq = 0; qq < 8; ++qq) {
        float m = -1e30f;
        for (int j = tid; j < LQ; j += 256) m = fmaxf(m, sc[qq][j]);
        for (int o = 32; o > 0; o >>= 1) m = fmaxf(m, __shfl_down(m, o, 64));
        if ((tid & 63) == 0) red[tid >> 6] = m;
        __syncthreads();
        m = fmaxf(fmaxf(red[0], red[1]), fmaxf(red[2], red[3]));
        __syncthreads();
        float s = 0.f;
        for (int j = tid; j < LQ; j += 256) {
            float e = __expf(sc[qq][j] - m);
            sc[qq][j] = e;
            s += e;
        }
        for (int o = 32; o > 0; o >>= 1) s += __shfl_down(s, o, 64);
        if ((tid & 63) == 0) red[tid >> 6] = s;
        __syncthreads();
        s = red[0] + red[1] + red[2] + red[3];
        float inv = 1.0f / s;
        for (int j = tid; j < LQ; j += 256) sc[qq][j] *= inv;
        __syncthreads();
    }

    // P @ V
    float acc = 0.f;
    const int qq = tid >> 5, d = tid & 31;
    for (int jt = 0; jt < LQ; jt += 128) {
        int cnt = min(128, LQ - jt);
        __syncthreads();
        for (int e = tid; e < cnt * 32; e += 256) {
            int row = e >> 5, col = e & 31;
            ks[row][col] = v[((size_t)(n * LQ + jt + row)) * D + h * DH + col];
        }
        __syncthreads();
        for (int j = 0; j < cnt; ++j) acc += sc[qq][jt + j] * ks[j][d];
    }
    out[((size_t)(n * LQ + q0 + qq)) * D + h * DH + d] = acc;
}

// ---------------- residual + layernorm ----------------
__global__ __launch_bounds__(256) void ln_res_kernel(const float* __restrict__ base, const float* __restrict__ delta,
                                                     const float* __restrict__ g, const float* __restrict__ b,
                                                     float* __restrict__ out) {
    __shared__ float scratch[8];
    const size_t row = blockIdx.x;
    const int d = threadIdx.x;
    float x = base[row * D + d] + delta[row * D + d];
    float s1 = x, s2 = x * x;
    for (int o = 32; o > 0; o >>= 1) {
        s1 += __shfl_down(s1, o, 64);
        s2 += __shfl_down(s2, o, 64);
    }
    const int w = threadIdx.x >> 6, lane = threadIdx.x & 63;
    if (lane == 0) { scratch[w] = s1; scratch[4 + w] = s2; }
    __syncthreads();
    s1 = scratch[0] + scratch[1] + scratch[2] + scratch[3];
    s2 = scratch[4] + scratch[5] + scratch[6] + scratch[7];
    float mean = s1 * (1.0f / 256.0f);
    float var = s2 * (1.0f / 256.0f) - mean * mean;
    float rstd = rsqrtf(var + 1e-5f);
    float y = (x - mean) * rstd * g[d] + b[d];
    out[row * D + d] = y;
}

// ---------------- softmax over 16 (NL*NP) ----------------
__global__ __launch_bounds__(256) void aw_softmax_kernel(float* __restrict__ aw, int ngrp) {
    int t = blockIdx.x * 256 + threadIdx.x;
    if (t >= ngrp) return;
    float* p = aw + (size_t)t * 16;
    float m = p[0];
#pragma unroll
    for (int i = 1; i < 16; ++i) m = fmaxf(m, p[i]);
    float s = 0.f;
    float e[16];
#pragma unroll
    for (int i = 0; i < 16; ++i) { e[i] = __expf(p[i] - m); s += e[i]; }
    float inv = 1.0f / s;
#pragma unroll
    for (int i = 0; i < 16; ++i) p[i] = e[i] * inv;
}

// ---------------- MS-deformable bilinear sampling ----------------
__global__ __launch_bounds__(64) void deform_kernel(const bf16* __restrict__ value, const float* __restrict__ offs,
                                                    const float* __restrict__ aw, const float* __restrict__ refp,
                                                    float* __restrict__ out) {
    const int qi = blockIdx.x, h = blockIdx.y, n = blockIdx.z;
    const int d = threadIdx.x & 31, half = threadIdx.x >> 5;
    const size_t row = (size_t)n * LQ + qi;
    const int HL[4] = {128, 64, 32, 16};
    const int WL[4] = {128, 64, 32, 16};
    const int START[4] = {0, 16384, 20480, 21504};
    float acc = 0.f;
    for (int lp = half * 8; lp < half * 8 + 8; ++lp) {
        int l = lp >> 2, p = lp & 3;
        int W = WL[l], H = HL[l];
        float rx = refp[(row * NL + l) * 2 + 0];
        float ry = refp[(row * NL + l) * 2 + 1];
        float ox = offs[row * D + ((h * NL + l) * NP + p) * 2 + 0];
        float oy = offs[row * D + ((h * NL + l) * NP + p) * 2 + 1];
        float w_attn = aw[row * 128 + h * 16 + lp];
        float x = (rx + ox / W) * W - 0.5f;
        float y = (ry + oy / H) * H - 0.5f;
        float x0 = floorf(x), y0 = floorf(y);
        float lx = x - x0, ly = y - y0;
        int x0i = (int)x0, y0i = (int)y0;
        float sample = 0.f;
#pragma unroll
        for (int c = 0; c < 4; ++c) {
            int dy = c >> 1, dx = c & 1;
            int xi = x0i + dx, yi = y0i + dy;
            if (xi >= 0 && xi < W && yi >= 0 && yi < H) {
                float wgt = (dy ? ly : 1.f - ly) * (dx ? lx : 1.f - lx);
                size_t vrow = (size_t)n * LEN_IN + START[l] + yi * W + xi;
                sample += wgt * toF(value[vrow * D + h * DH + d]);
            }
        }
        acc += w_attn * sample;
    }
    acc += __shfl_down(acc, 32, 64);
    if (half == 0) out[row * D + h * DH + d] = acc;
}

// ---------------- host ----------------
extern "C" void kernel_launch(void* const* d_in, const int* in_sizes, int n_in,
                              void* d_out, int out_size, void* d_ws, size_t ws_size,
                              hipStream_t stream) {
    const float* tgt = (const float*)d_in[0];
    const float* qpos = (const float*)d_in[1];
    const float* refp = (const float*)d_in[2];
    const float* src = (const float*)d_in[3];
    const float* sa_in_w = (const float*)d_in[6];
    const float* sa_in_b = (const float*)d_in[7];
    const float* sa_out_w = (const float*)d_in[8];
    const float* sa_out_b = (const float*)d_in[9];
    const float* norm2_g = (const float*)d_in[10];
    const float* norm2_b = (const float*)d_in[11];
    const float* off_w = (const float*)d_in[12];
    const float* off_b = (const float*)d_in[13];
    const float* aw_w = (const float*)d_in[14];
    const float* aw_b = (const float*)d_in[15];
    const float* val_w = (const float*)d_in[16];
    const float* val_b = (const float*)d_in[17];
    const float* outp_w = (const float*)d_in[18];
    const float* outp_b = (const float*)d_in[19];
    const float* norm1_g = (const float*)d_in[20];
    const float* norm1_b = (const float*)d_in[21];
    const float* ffn_w1 = (const float*)d_in[22];
    const float* ffn_b1 = (const float*)d_in[23];
    const float* ffn_w2 = (const float*)d_in[24];
    const float* ffn_b2 = (const float*)d_in[25];
    const float* norm3_g = (const float*)d_in[26];
    const float* norm3_b = (const float*)d_in[27];
    float* outp = (float*)d_out;

    const size_t NTOK = (size_t)NB * LQ;          // 8000
    const size_t NE = NTOK * D;                   // 2,048,000
    float* w = (float*)d_ws;
    size_t off = 0;
    auto alloc = [&](size_t n) { float* p = w + off; off += n; return p; };
    float* bufA = alloc(NE);          // qk -> att -> dout
    float* bufB = alloc(NE);          // qb -> sap -> ca
    float* bufC = alloc(NE);          // kb -> qry -> ff
    float* bufD = alloc(NE);          // vb -> offs
    float* tgt2 = alloc(NE);
    float* tgt3 = alloc(NE);
    float* awb = alloc(NTOK * 128);
    float* mid = alloc(NTOK * DFFN);
    bf16* value = (bf16*)(w + off);   // (NB*LEN_IN, D) bf16

    const int ne = (int)NE;
    dim3 g64(256 / 64, (NTOK + 63) / 64);

    // ---- self attention ----
    add_ff<<<(ne + 255) / 256, 256, 0, stream>>>(tgt, qpos, bufA, ne);  // qk
    gemm_kernel<float><<<g64, 256, 0, stream>>>(bufA, sa_in_w, sa_in_b, bufB, (int)NTOK, D, D, 0);              // Q
    gemm_kernel<float><<<g64, 256, 0, stream>>>(bufA, sa_in_w + 256 * 256, sa_in_b + 256, bufC, (int)NTOK, D, D, 0); // K
    gemm_kernel<float><<<g64, 256, 0, stream>>>(tgt, sa_in_w + 512 * 256, sa_in_b + 512, bufD, (int)NTOK, D, D, 0);  // V
    attn_kernel<<<dim3(LQ / 8, NH, NB), 256, 0, stream>>>(bufB, bufC, bufD, bufA);                              // att
    gemm_kernel<float><<<g64, 256, 0, stream>>>(bufA, sa_out_w, sa_out_b, bufB, (int)NTOK, D, D, 0);            // sap
    ln_res_kernel<<<NTOK, 256, 0, stream>>>(tgt, bufB, norm2_g, norm2_b, tgt2);

    // ---- deformable attention ----
    add_ff<<<(ne + 255) / 256, 256, 0, stream>>>(tgt2, qpos, bufC, ne);  // query
    gemm_kernel<bf16><<<dim3(256 / 64, (NB * LEN_IN) / 64), 256, 0, stream>>>(src, val_w, val_b, value,
                                                                              NB * LEN_IN, D, D, 0);
    gemm_kernel<float><<<g64, 256, 0, stream>>>(bufC, off_w, off_b, bufD, (int)NTOK, D, D, 0);   // offsets
    gemm_kernel<float><<<dim3(128 / 64, (NTOK + 63) / 64), 256, 0, stream>>>(bufC, aw_w, aw_b, awb,
                                                                             (int)NTOK, 128, D, 0);
    aw_softmax_kernel<<<(int)(NTOK * NH + 255) / 256, 256, 0, stream>>>(awb, (int)(NTOK * NH));
    deform_kernel<<<dim3(LQ, NH, NB), 64, 0, stream>>>(value, bufD, awb, refp, bufA);            // dout
    gemm_kernel<float><<<g64, 256, 0, stream>>>(bufA, outp_w, outp_b, bufB, (int)NTOK, D, D, 0); // ca
    ln_res_kernel<<<NTOK, 256, 0, stream>>>(tgt2, bufB, norm1_g, norm1_b, tgt3);

    // ---- FFN ----
    gemm_kernel<float><<<dim3(DFFN / 64, (NTOK + 63) / 64), 256, 0, stream>>>(tgt3, ffn_w1, ffn_b1, mid,
                                                                              (int)NTOK, DFFN, D, 1);
    gemm_kernel<float><<<g64, 256, 0, stream>>>(mid, ffn_w2, ffn_b2, bufC, (int)NTOK, D, DFFN, 0); // ff
    ln_res_kernel<<<NTOK, 256, 0, stream>>>(tgt3, bufC, norm3_g, norm3_b, outp);
}

// Round 3
// 1667.993 us; speedup vs baseline: 7.1713x; 7.1713x over previous
//
#include <hip/hip_runtime.h>
#include <hip/hip_bf16.h>

#define D 256
#define NH 8
#define DH 32
#define NL 4
#define NP 4
#define DFFN 1024
#define LEN_IN 21760
#define NB 8
#define LQ 1000

typedef __hip_bfloat16 bf16;

__device__ inline float toF(float x) { return x; }
__device__ inline float toF(bf16 x) { return __bfloat162float(x); }

template <typename T> __device__ inline T fromF(float x);
template <> __device__ inline float fromF<float>(float x) { return x; }
template <> __device__ inline bf16 fromF<bf16>(float x) { return __float2bfloat16(x); }

// ---------------- elementwise add ----------------
__global__ __launch_bounds__(256) void add_ff(const float* __restrict__ a, const float* __restrict__ b,
                                              float* __restrict__ o, int n) {
    int i = blockIdx.x * 256 + threadIdx.x;
    if (i < n) o[i] = a[i] + b[i];
}

// ---------------- GEMM: C[M,N] = A[M,K] @ W[N,K]^T + bias, optional relu ----------------
template <typename TC>
__global__ __launch_bounds__(256) void gemm_kernel(const float* __restrict__ A, const float* __restrict__ W,
                                                   const float* __restrict__ bias, TC* __restrict__ C,
                                                   int M, int N, int K, int do_relu) {
    __shared__ float As[16][65];
    __shared__ float Bs[16][65];
    const int tid = threadIdx.x;
    const int m0 = blockIdx.y * 64, n0 = blockIdx.x * 64;
    const int tm = (tid >> 4) << 2;
    const int tn = (tid & 15) << 2;
    const int lr = tid >> 2;          // 0..63
    const int lc = (tid & 3) << 2;    // 0,4,8,12
    float acc[4][4] = {};
    for (int k0 = 0; k0 < K; k0 += 16) {
        const float* ap = A + (size_t)(m0 + lr) * K + (k0 + lc);
        const float* wp = W + (size_t)(n0 + lr) * K + (k0 + lc);
        float a0 = ap[0], a1 = ap[1], a2 = ap[2], a3 = ap[3];
        float b0 = wp[0], b1 = wp[1], b2 = wp[2], b3 = wp[3];
        As[lc + 0][lr] = a0; As[lc + 1][lr] = a1; As[lc + 2][lr] = a2; As[lc + 3][lr] = a3;
        Bs[lc + 0][lr] = b0; Bs[lc + 1][lr] = b1; Bs[lc + 2][lr] = b2; Bs[lc + 3][lr] = b3;
        __syncthreads();
#pragma unroll
        for (int kk = 0; kk < 16; ++kk) {
            float av[4], bv[4];
#pragma unroll
            for (int i = 0; i < 4; ++i) av[i] = As[kk][tm + i];
#pragma unroll
            for (int j = 0; j < 4; ++j) bv[j] = Bs[kk][tn + j];
#pragma unroll
            for (int i = 0; i < 4; ++i)
#pragma unroll
                for (int j = 0; j < 4; ++j) acc[i][j] += av[i] * bv[j];
        }
        __syncthreads();
    }
#pragma unroll
    for (int i = 0; i < 4; ++i) {
        int m = m0 + tm + i;
        if (m < M) {
#pragma unroll
            for (int j = 0; j < 4; ++j) {
                int nn = n0 + tn + j;
                float r = acc[i][j] + bias[nn];
                if (do_relu) r = fmaxf(r, 0.0f);
                C[(size_t)m * N + nn] = fromF<TC>(r);
            }
        }
    }
}

// ---------------- flash-style self-attention ----------------
// grid (ceil(LQ/32), NH, NB), block 256. Thread owns query row r = tid>>3,
// 8 key-cols per tile (cg = (tid&7)*8). Q row in regs; online softmax;
// partial O in regs, reduced across the 8 row-lanes at the end.
__global__ __launch_bounds__(256) void attn_kernel(const float* __restrict__ q, const float* __restrict__ k,
                                                   const float* __restrict__ v, float* __restrict__ out) {
    const int q0 = blockIdx.x * 32;
    const int h = blockIdx.y;
    const int n = blockIdx.z;
    __shared__ float Ks[64][33];
    __shared__ float Vs[64][33];
    const int tid = threadIdx.x;
    const int r = tid >> 3;         // 0..31
    const int cg = (tid & 7) * 8;   // 0..56

    float qreg[32];
    {
        int qrow = (q0 + r < LQ) ? (q0 + r) : (LQ - 1);
        const float* qp = q + ((size_t)(n * LQ + qrow)) * D + h * DH;
#pragma unroll
        for (int d0 = 0; d0 < 32; d0 += 4) {
            float4 t = *(const float4*)(qp + d0);
            qreg[d0 + 0] = t.x * 0.17677669529663687f;
            qreg[d0 + 1] = t.y * 0.17677669529663687f;
            qreg[d0 + 2] = t.z * 0.17677669529663687f;
            qreg[d0 + 3] = t.w * 0.17677669529663687f;
        }
    }

    float m = -1e30f, l = 0.f;
    float O[32];
#pragma unroll
    for (int d = 0; d < 32; ++d) O[d] = 0.f;

    for (int jt = 0; jt < LQ; jt += 64) {
        int cnt = min(64, LQ - jt);
        __syncthreads();
        for (int e = tid; e < 64 * 32; e += 256) {
            int row = e >> 5, col = e & 31;
            int grow = (jt + row < LQ) ? (jt + row) : (LQ - 1);
            size_t gi = ((size_t)(n * LQ + grow)) * D + h * DH + col;
            Ks[row][col] = k[gi];
            Vs[row][col] = v[gi];
        }
        __syncthreads();

        float s[8];
#pragma unroll
        for (int j = 0; j < 8; ++j) {
            int c = cg + j;
            float dot = 0.f;
#pragma unroll
            for (int d = 0; d < 32; ++d) dot += qreg[d] * Ks[c][d];
            s[j] = (c < cnt) ? dot : -1e30f;
        }
        float rmax = s[0];
#pragma unroll
        for (int j = 1; j < 8; ++j) rmax = fmaxf(rmax, s[j]);
        rmax = fmaxf(rmax, __shfl_xor(rmax, 1, 64));
        rmax = fmaxf(rmax, __shfl_xor(rmax, 2, 64));
        rmax = fmaxf(rmax, __shfl_xor(rmax, 4, 64));

        float newm = fmaxf(m, rmax);
        float alpha = __expf(m - newm);
        m = newm;
        float p[8];
        float psum = 0.f;
#pragma unroll
        for (int j = 0; j < 8; ++j) { p[j] = __expf(s[j] - m); psum += p[j]; }
        psum += __shfl_xor(psum, 1, 64);
        psum += __shfl_xor(psum, 2, 64);
        psum += __shfl_xor(psum, 4, 64);
        l = l * alpha + psum;

#pragma unroll
        for (int d = 0; d < 32; ++d) O[d] *= alpha;
#pragma unroll
        for (int j = 0; j < 8; ++j) {
            int c = cg + j;
#pragma unroll
            for (int d = 0; d < 32; ++d) O[d] += p[j] * Vs[c][d];
        }
    }

#pragma unroll
    for (int d = 0; d < 32; ++d) {
        O[d] += __shfl_xor(O[d], 1, 64);
        O[d] += __shfl_xor(O[d], 2, 64);
        O[d] += __shfl_xor(O[d], 4, 64);
    }
    if (q0 + r < LQ) {
        float inv = 1.0f / l;
        float* op = out + ((size_t)(n * LQ + q0 + r)) * D + h * DH;
        int d0 = (tid & 7) * 4;
#pragma unroll
        for (int j = 0; j < 4; ++j) op[d0 + j] = O[d0 + j] * inv;
    }
}

// ---------------- residual + layernorm ----------------
__global__ __launch_bounds__(256) void ln_res_kernel(const float* __restrict__ base, const float* __restrict__ delta,
                                                     const float* __restrict__ g, const float* __restrict__ b,
                                                     float* __restrict__ out) {
    __shared__ float scratch[8];
    const size_t row = blockIdx.x;
    const int d = threadIdx.x;
    float x = base[row * D + d] + delta[row * D + d];
    float s1 = x, s2 = x * x;
    for (int o = 32; o > 0; o >>= 1) {
        s1 += __shfl_down(s1, o, 64);
        s2 += __shfl_down(s2, o, 64);
    }
    const int w = threadIdx.x >> 6, lane = threadIdx.x & 63;
    if (lane == 0) { scratch[w] = s1; scratch[4 + w] = s2; }
    __syncthreads();
    s1 = scratch[0] + scratch[1] + scratch[2] + scratch[3];
    s2 = scratch[4] + scratch[5] + scratch[6] + scratch[7];
    float mean = s1 * (1.0f / 256.0f);
    float var = s2 * (1.0f / 256.0f) - mean * mean;
    float rstd = rsqrtf(var + 1e-5f);
    float y = (x - mean) * rstd * g[d] + b[d];
    out[row * D + d] = y;
}

// ---------------- softmax over 16 (NL*NP) ----------------
__global__ __launch_bounds__(256) void aw_softmax_kernel(float* __restrict__ aw, int ngrp) {
    int t = blockIdx.x * 256 + threadIdx.x;
    if (t >= ngrp) return;
    float* p = aw + (size_t)t * 16;
    float m = p[0];
#pragma unroll
    for (int i = 1; i < 16; ++i) m = fmaxf(m, p[i]);
    float s = 0.f;
    float e[16];
#pragma unroll
    for (int i = 0; i < 16; ++i) { e[i] = __expf(p[i] - m); s += e[i]; }
    float inv = 1.0f / s;
#pragma unroll
    for (int i = 0; i < 16; ++i) p[i] = e[i] * inv;
}

// ---------------- MS-deformable bilinear sampling ----------------
__global__ __launch_bounds__(64) void deform_kernel(const bf16* __restrict__ value, const float* __restrict__ offs,
                                                    const float* __restrict__ aw, const float* __restrict__ refp,
                                                    float* __restrict__ out) {
    const int qi = blockIdx.x, h = blockIdx.y, n = blockIdx.z;
    const int d = threadIdx.x & 31, half = threadIdx.x >> 5;
    const size_t row = (size_t)n * LQ + qi;
    const int HL[4] = {128, 64, 32, 16};
    const int WL[4] = {128, 64, 32, 16};
    const int START[4] = {0, 16384, 20480, 21504};
    float acc = 0.f;
    for (int lp = half * 8; lp < half * 8 + 8; ++lp) {
        int l = lp >> 2, p = lp & 3;
        int W = WL[l], H = HL[l];
        float rx = refp[(row * NL + l) * 2 + 0];
        float ry = refp[(row * NL + l) * 2 + 1];
        float ox = offs[row * D + ((h * NL + l) * NP + p) * 2 + 0];
        float oy = offs[row * D + ((h * NL + l) * NP + p) * 2 + 1];
        float w_attn = aw[row * 128 + h * 16 + lp];
        float x = (rx + ox / W) * W - 0.5f;
        float y = (ry + oy / H) * H - 0.5f;
        float x0 = floorf(x), y0 = floorf(y);
        float lx = x - x0, ly = y - y0;
        int x0i = (int)x0, y0i = (int)y0;
        float sample = 0.f;
#pragma unroll
        for (int c = 0; c < 4; ++c) {
            int dy = c >> 1, dx = c & 1;
            int xi = x0i + dx, yi = y0i + dy;
            if (xi >= 0 && xi < W && yi >= 0 && yi < H) {
                float wgt = (dy ? ly : 1.f - ly) * (dx ? lx : 1.f - lx);
                size_t vrow = (size_t)n * LEN_IN + START[l] + yi * W + xi;
                sample += wgt * toF(value[vrow * D + h * DH + d]);
            }
        }
        acc += w_attn * sample;
    }
    acc += __shfl_down(acc, 32, 64);
    if (half == 0) out[row * D + h * DH + d] = acc;
}

// ---------------- host ----------------
extern "C" void kernel_launch(void* const* d_in, const int* in_sizes, int n_in,
                              void* d_out, int out_size, void* d_ws, size_t ws_size,
                              hipStream_t stream) {
    const float* tgt = (const float*)d_in[0];
    const float* qpos = (const float*)d_in[1];
    const float* refp = (const float*)d_in[2];
    const float* src = (const float*)d_in[3];
    const float* sa_in_w = (const float*)d_in[6];
    const float* sa_in_b = (const float*)d_in[7];
    const float* sa_out_w = (const float*)d_in[8];
    const float* sa_out_b = (const float*)d_in[9];
    const float* norm2_g = (const float*)d_in[10];
    const float* norm2_b = (const float*)d_in[11];
    const float* off_w = (const float*)d_in[12];
    const float* off_b = (const float*)d_in[13];
    const float* aw_w = (const float*)d_in[14];
    const float* aw_b = (const float*)d_in[15];
    const float* val_w = (const float*)d_in[16];
    const float* val_b = (const float*)d_in[17];
    const float* outp_w = (const float*)d_in[18];
    const float* outp_b = (const float*)d_in[19];
    const float* norm1_g = (const float*)d_in[20];
    const float* norm1_b = (const float*)d_in[21];
    const float* ffn_w1 = (const float*)d_in[22];
    const float* ffn_b1 = (const float*)d_in[23];
    const float* ffn_w2 = (const float*)d_in[24];
    const float* ffn_b2 = (const float*)d_in[25];
    const float* norm3_g = (const float*)d_in[26];
    const float* norm3_b = (const float*)d_in[27];
    float* outp = (float*)d_out;

    const size_t NTOK = (size_t)NB * LQ;          // 8000
    const size_t NE = NTOK * D;                   // 2,048,000
    float* w = (float*)d_ws;
    size_t off = 0;
    auto alloc = [&](size_t n) { float* p = w + off; off += n; return p; };
    float* bufA = alloc(NE);          // qk -> att -> dout
    float* bufB = alloc(NE);          // qb -> sap -> ca
    float* bufC = alloc(NE);          // kb -> qry -> ff
    float* bufD = alloc(NE);          // vb -> offs
    float* tgt2 = alloc(NE);
    float* tgt3 = alloc(NE);
    float* awb = alloc(NTOK * 128);
    float* mid = alloc(NTOK * DFFN);
    bf16* value = (bf16*)(w + off);   // (NB*LEN_IN, D) bf16

    const int ne = (int)NE;
    dim3 g64(256 / 64, (NTOK + 63) / 64);

    // ---- self attention ----
    add_ff<<<(ne + 255) / 256, 256, 0, stream>>>(tgt, qpos, bufA, ne);  // qk
    gemm_kernel<float><<<g64, 256, 0, stream>>>(bufA, sa_in_w, sa_in_b, bufB, (int)NTOK, D, D, 0);              // Q
    gemm_kernel<float><<<g64, 256, 0, stream>>>(bufA, sa_in_w + 256 * 256, sa_in_b + 256, bufC, (int)NTOK, D, D, 0); // K
    gemm_kernel<float><<<g64, 256, 0, stream>>>(tgt, sa_in_w + 512 * 256, sa_in_b + 512, bufD, (int)NTOK, D, D, 0);  // V
    attn_kernel<<<dim3((LQ + 31) / 32, NH, NB), 256, 0, stream>>>(bufB, bufC, bufD, bufA);                      // att
    gemm_kernel<float><<<g64, 256, 0, stream>>>(bufA, sa_out_w, sa_out_b, bufB, (int)NTOK, D, D, 0);            // sap
    ln_res_kernel<<<NTOK, 256, 0, stream>>>(tgt, bufB, norm2_g, norm2_b, tgt2);

    // ---- deformable attention ----
    add_ff<<<(ne + 255) / 256, 256, 0, stream>>>(tgt2, qpos, bufC, ne);  // query
    gemm_kernel<bf16><<<dim3(256 / 64, (NB * LEN_IN) / 64), 256, 0, stream>>>(src, val_w, val_b, value,
                                                                              NB * LEN_IN, D, D, 0);
    gemm_kernel<float><<<g64, 256, 0, stream>>>(bufC, off_w, off_b, bufD, (int)NTOK, D, D, 0);   // offsets
    gemm_kernel<float><<<dim3(128 / 64, (NTOK + 63) / 64), 256, 0, stream>>>(bufC, aw_w, aw_b, awb,
                                                                             (int)NTOK, 128, D, 0);
    aw_softmax_kernel<<<(int)(NTOK * NH + 255) / 256, 256, 0, stream>>>(awb, (int)(NTOK * NH));
    deform_kernel<<<dim3(LQ, NH, NB), 64, 0, stream>>>(value, bufD, awb, refp, bufA);            // dout
    gemm_kernel<float><<<g64, 256, 0, stream>>>(bufA, outp_w, outp_b, bufB, (int)NTOK, D, D, 0); // ca
    ln_res_kernel<<<NTOK, 256, 0, stream>>>(tgt2, bufB, norm1_g, norm1_b, tgt3);

    // ---- FFN ----
    gemm_kernel<float><<<dim3(DFFN / 64, (NTOK + 63) / 64), 256, 0, stream>>>(tgt3, ffn_w1, ffn_b1, mid,
                                                                              (int)NTOK, DFFN, D, 1);
    gemm_kernel<float><<<g64, 256, 0, stream>>>(mid, ffn_w2, ffn_b2, bufC, (int)NTOK, D, DFFN, 0); // ff
    ln_res_kernel<<<NTOK, 256, 0, stream>>>(tgt3, bufC, norm3_g, norm3_b, outp);
}

// Round 4
// 1170.099 us; speedup vs baseline: 10.2228x; 1.4255x over previous
//
#include <hip/hip_runtime.h>
#include <hip/hip_bf16.h>

#define D 256
#define NH 8
#define DH 32
#define NL 4
#define NP 4
#define DFFN 1024
#define LEN_IN 21760
#define NB 8
#define LQ 1000

typedef __hip_bfloat16 bf16;
typedef __attribute__((ext_vector_type(8))) short s8v;
typedef __attribute__((ext_vector_type(4))) float f4v;

__device__ inline float toF(float x) { return x; }
__device__ inline float toF(bf16 x) { return __bfloat162float(x); }

template <typename T> __device__ inline T fromF(float x);
template <> __device__ inline float fromF<float>(float x) { return x; }
template <> __device__ inline bf16 fromF<bf16>(float x) { return __float2bfloat16(x); }

// fp32 -> bf16 round-to-nearest-even, branchless (finite inputs)
__device__ inline short bfr(float f) {
    unsigned u = __float_as_uint(f);
    u += 0x7fff + ((u >> 16) & 1);
    return (short)(u >> 16);
}
__device__ inline s8v pack8(float4 x, float4 y) {
    s8v r;
    r[0] = bfr(x.x); r[1] = bfr(x.y); r[2] = bfr(x.z); r[3] = bfr(x.w);
    r[4] = bfr(y.x); r[5] = bfr(y.y); r[6] = bfr(y.z); r[7] = bfr(y.w);
    return r;
}

// ---------------- MFMA GEMM: C[M,N] = (A(+A2))[M,K] @ W[N,K]^T + bias, optional relu ----
// 128x128 tile, BK=32, 4 waves each computing 64x64 via 4x4 mfma_f32_16x16x32_bf16.
// A: float (converted to bf16 in staging, optional fused add of A2) or bf16.
template <typename TA, typename TC>
__global__ __launch_bounds__(256) void mfma_gemm(const TA* __restrict__ A, const float* __restrict__ A2,
                                                 const float* __restrict__ W, const float* __restrict__ bias,
                                                 TC* __restrict__ C, int M, int N, int K, int do_relu) {
    constexpr int LDT = 40;                 // bf16 elems per LDS row (80 B, 16B-aligned frags)
    __shared__ bf16 As[128 * LDT];
    __shared__ bf16 Bs[128 * LDT];
    const int tid = threadIdx.x;
    const int m0 = blockIdx.y * 128, n0 = blockIdx.x * 128;
    const int srow = tid >> 1;              // 0..127 staging row
    const int sks = (tid & 1) * 16;         // k-offset 0/16
    const int lane = tid & 63;
    const int wave = tid >> 6;
    const int wm = (wave >> 1) * 64, wn = (wave & 1) * 64;
    const int fr = lane & 15, fq = lane >> 4;

    int arow = m0 + srow; if (arow >= M) arow = M - 1;   // clamp tail loads
    const TA* aptr = A + (size_t)arow * K + sks;
    const float* a2ptr = A2 ? (A2 + (size_t)arow * K + sks) : nullptr;
    const float* wptr = W + (size_t)(n0 + srow) * K + sks;

    f4v acc[4][4];
#pragma unroll
    for (int i = 0; i < 4; ++i)
#pragma unroll
        for (int j = 0; j < 4; ++j) acc[i][j] = (f4v){0.f, 0.f, 0.f, 0.f};

    for (int k0 = 0; k0 < K; k0 += 32) {
        s8v av0, av1, wv0, wv1;
        if constexpr (sizeof(TA) == 2) {
            av0 = *(const s8v*)((const bf16*)aptr + k0);
            av1 = *(const s8v*)((const bf16*)aptr + k0 + 8);
        } else {
            float4 a0 = *(const float4*)(aptr + k0);
            float4 a1 = *(const float4*)(aptr + k0 + 4);
            float4 a2 = *(const float4*)(aptr + k0 + 8);
            float4 a3 = *(const float4*)(aptr + k0 + 12);
            if (a2ptr) {
                float4 b0 = *(const float4*)(a2ptr + k0);
                float4 b1 = *(const float4*)(a2ptr + k0 + 4);
                float4 b2 = *(const float4*)(a2ptr + k0 + 8);
                float4 b3 = *(const float4*)(a2ptr + k0 + 12);
                a0.x += b0.x; a0.y += b0.y; a0.z += b0.z; a0.w += b0.w;
                a1.x += b1.x; a1.y += b1.y; a1.z += b1.z; a1.w += b1.w;
                a2.x += b2.x; a2.y += b2.y; a2.z += b2.z; a2.w += b2.w;
                a3.x += b3.x; a3.y += b3.y; a3.z += b3.z; a3.w += b3.w;
            }
            av0 = pack8(a0, a1);
            av1 = pack8(a2, a3);
        }
        {
            float4 w0 = *(const float4*)(wptr + k0);
            float4 w1 = *(const float4*)(wptr + k0 + 4);
            float4 w2 = *(const float4*)(wptr + k0 + 8);
            float4 w3 = *(const float4*)(wptr + k0 + 12);
            wv0 = pack8(w0, w1);
            wv1 = pack8(w2, w3);
        }
        __syncthreads();   // previous iteration's frag reads done
        *(s8v*)&As[srow * LDT + sks] = av0;
        *(s8v*)&As[srow * LDT + sks + 8] = av1;
        *(s8v*)&Bs[srow * LDT + sks] = wv0;
        *(s8v*)&Bs[srow * LDT + sks + 8] = wv1;
        __syncthreads();
        s8v af[4], bfv[4];
#pragma unroll
        for (int i = 0; i < 4; ++i) af[i] = *(s8v*)&As[(wm + i * 16 + fr) * LDT + fq * 8];
#pragma unroll
        for (int j = 0; j < 4; ++j) bfv[j] = *(s8v*)&Bs[(wn + j * 16 + fr) * LDT + fq * 8];
#pragma unroll
        for (int i = 0; i < 4; ++i)
#pragma unroll
            for (int j = 0; j < 4; ++j)
                acc[i][j] = __builtin_amdgcn_mfma_f32_16x16x32_bf16(af[i], bfv[j], acc[i][j], 0, 0, 0);
    }

#pragma unroll
    for (int i = 0; i < 4; ++i) {
        int rbase = m0 + wm + i * 16 + fq * 4;
#pragma unroll
        for (int r = 0; r < 4; ++r) {
            int row = rbase + r;
            if (row < M) {
#pragma unroll
                for (int j = 0; j < 4; ++j) {
                    int col = n0 + wn + j * 16 + fr;
                    float v = acc[i][j][r] + bias[col];
                    if (do_relu) v = fmaxf(v, 0.f);
                    C[(size_t)row * N + col] = fromF<TC>(v);
                }
            }
        }
    }
}

// ---------------- flash-style self-attention ----------------
__global__ __launch_bounds__(256) void attn_kernel(const float* __restrict__ q, const float* __restrict__ k,
                                                   const float* __restrict__ v, float* __restrict__ out) {
    const int q0 = blockIdx.x * 32;
    const int h = blockIdx.y;
    const int n = blockIdx.z;
    __shared__ float Ks[64][33];
    __shared__ float Vs[64][33];
    const int tid = threadIdx.x;
    const int r = tid >> 3;         // 0..31
    const int cg = (tid & 7) * 8;   // 0..56

    float qreg[32];
    {
        int qrow = (q0 + r < LQ) ? (q0 + r) : (LQ - 1);
        const float* qp = q + ((size_t)(n * LQ + qrow)) * D + h * DH;
#pragma unroll
        for (int d0 = 0; d0 < 32; d0 += 4) {
            float4 t = *(const float4*)(qp + d0);
            qreg[d0 + 0] = t.x * 0.17677669529663687f;
            qreg[d0 + 1] = t.y * 0.17677669529663687f;
            qreg[d0 + 2] = t.z * 0.17677669529663687f;
            qreg[d0 + 3] = t.w * 0.17677669529663687f;
        }
    }

    float m = -1e30f, l = 0.f;
    float O[32];
#pragma unroll
    for (int d = 0; d < 32; ++d) O[d] = 0.f;

    for (int jt = 0; jt < LQ; jt += 64) {
        int cnt = min(64, LQ - jt);
        __syncthreads();
        for (int e = tid; e < 64 * 32; e += 256) {
            int row = e >> 5, col = e & 31;
            int grow = (jt + row < LQ) ? (jt + row) : (LQ - 1);
            size_t gi = ((size_t)(n * LQ + grow)) * D + h * DH + col;
            Ks[row][col] = k[gi];
            Vs[row][col] = v[gi];
        }
        __syncthreads();

        float s[8];
#pragma unroll
        for (int j = 0; j < 8; ++j) {
            int c = cg + j;
            float dot = 0.f;
#pragma unroll
            for (int d = 0; d < 32; ++d) dot += qreg[d] * Ks[c][d];
            s[j] = (c < cnt) ? dot : -1e30f;
        }
        float rmax = s[0];
#pragma unroll
        for (int j = 1; j < 8; ++j) rmax = fmaxf(rmax, s[j]);
        rmax = fmaxf(rmax, __shfl_xor(rmax, 1, 64));
        rmax = fmaxf(rmax, __shfl_xor(rmax, 2, 64));
        rmax = fmaxf(rmax, __shfl_xor(rmax, 4, 64));

        float newm = fmaxf(m, rmax);
        float alpha = __expf(m - newm);
        m = newm;
        float p[8];
        float psum = 0.f;
#pragma unroll
        for (int j = 0; j < 8; ++j) { p[j] = __expf(s[j] - m); psum += p[j]; }
        psum += __shfl_xor(psum, 1, 64);
        psum += __shfl_xor(psum, 2, 64);
        psum += __shfl_xor(psum, 4, 64);
        l = l * alpha + psum;

#pragma unroll
        for (int d = 0; d < 32; ++d) O[d] *= alpha;
#pragma unroll
        for (int j = 0; j < 8; ++j) {
            int c = cg + j;
#pragma unroll
            for (int d = 0; d < 32; ++d) O[d] += p[j] * Vs[c][d];
        }
    }

#pragma unroll
    for (int d = 0; d < 32; ++d) {
        O[d] += __shfl_xor(O[d], 1, 64);
        O[d] += __shfl_xor(O[d], 2, 64);
        O[d] += __shfl_xor(O[d], 4, 64);
    }
    if (q0 + r < LQ) {
        float inv = 1.0f / l;
        float* op = out + ((size_t)(n * LQ + q0 + r)) * D + h * DH;
        int d0 = (tid & 7) * 4;
#pragma unroll
        for (int j = 0; j < 4; ++j) op[d0 + j] = O[d0 + j] * inv;
    }
}

// ---------------- residual + layernorm ----------------
__global__ __launch_bounds__(256) void ln_res_kernel(const float* __restrict__ base, const float* __restrict__ delta,
                                                     const float* __restrict__ g, const float* __restrict__ b,
                                                     float* __restrict__ out) {
    __shared__ float scratch[8];
    const size_t row = blockIdx.x;
    const int d = threadIdx.x;
    float x = base[row * D + d] + delta[row * D + d];
    float s1 = x, s2 = x * x;
    for (int o = 32; o > 0; o >>= 1) {
        s1 += __shfl_down(s1, o, 64);
        s2 += __shfl_down(s2, o, 64);
    }
    const int w = threadIdx.x >> 6, lane = threadIdx.x & 63;
    if (lane == 0) { scratch[w] = s1; scratch[4 + w] = s2; }
    __syncthreads();
    s1 = scratch[0] + scratch[1] + scratch[2] + scratch[3];
    s2 = scratch[4] + scratch[5] + scratch[6] + scratch[7];
    float mean = s1 * (1.0f / 256.0f);
    float var = s2 * (1.0f / 256.0f) - mean * mean;
    float rstd = rsqrtf(var + 1e-5f);
    float y = (x - mean) * rstd * g[d] + b[d];
    out[row * D + d] = y;
}

// ---------------- softmax over 16 (NL*NP) ----------------
__global__ __launch_bounds__(256) void aw_softmax_kernel(float* __restrict__ aw, int ngrp) {
    int t = blockIdx.x * 256 + threadIdx.x;
    if (t >= ngrp) return;
    float* p = aw + (size_t)t * 16;
    float m = p[0];
#pragma unroll
    for (int i = 1; i < 16; ++i) m = fmaxf(m, p[i]);
    float s = 0.f;
    float e[16];
#pragma unroll
    for (int i = 0; i < 16; ++i) { e[i] = __expf(p[i] - m); s += e[i]; }
    float inv = 1.0f / s;
#pragma unroll
    for (int i = 0; i < 16; ++i) p[i] = e[i] * inv;
}

// ---------------- MS-deformable bilinear sampling ----------------
__global__ __launch_bounds__(64) void deform_kernel(const bf16* __restrict__ value, const float* __restrict__ offs,
                                                    const float* __restrict__ aw, const float* __restrict__ refp,
                                                    float* __restrict__ out) {
    const int qi = blockIdx.x, h = blockIdx.y, n = blockIdx.z;
    const int d = threadIdx.x & 31, half = threadIdx.x >> 5;
    const size_t row = (size_t)n * LQ + qi;
    const int HL[4] = {128, 64, 32, 16};
    const int WL[4] = {128, 64, 32, 16};
    const int START[4] = {0, 16384, 20480, 21504};
    float acc = 0.f;
    for (int lp = half * 8; lp < half * 8 + 8; ++lp) {
        int l = lp >> 2, p = lp & 3;
        int W = WL[l], H = HL[l];
        float rx = refp[(row * NL + l) * 2 + 0];
        float ry = refp[(row * NL + l) * 2 + 1];
        float ox = offs[row * D + ((h * NL + l) * NP + p) * 2 + 0];
        float oy = offs[row * D + ((h * NL + l) * NP + p) * 2 + 1];
        float w_attn = aw[row * 128 + h * 16 + lp];
        float x = (rx + ox / W) * W - 0.5f;
        float y = (ry + oy / H) * H - 0.5f;
        float x0 = floorf(x), y0 = floorf(y);
        float lx = x - x0, ly = y - y0;
        int x0i = (int)x0, y0i = (int)y0;
        float sample = 0.f;
#pragma unroll
        for (int c = 0; c < 4; ++c) {
            int dy = c >> 1, dx = c & 1;
            int xi = x0i + dx, yi = y0i + dy;
            if (xi >= 0 && xi < W && yi >= 0 && yi < H) {
                float wgt = (dy ? ly : 1.f - ly) * (dx ? lx : 1.f - lx);
                size_t vrow = (size_t)n * LEN_IN + START[l] + yi * W + xi;
                sample += wgt * toF(value[vrow * D + h * DH + d]);
            }
        }
        acc += w_attn * sample;
    }
    acc += __shfl_down(acc, 32, 64);
    if (half == 0) out[row * D + h * DH + d] = acc;
}

// ---------------- host ----------------
extern "C" void kernel_launch(void* const* d_in, const int* in_sizes, int n_in,
                              void* d_out, int out_size, void* d_ws, size_t ws_size,
                              hipStream_t stream) {
    const float* tgt = (const float*)d_in[0];
    const float* qpos = (const float*)d_in[1];
    const float* refp = (const float*)d_in[2];
    const float* src = (const float*)d_in[3];
    const float* sa_in_w = (const float*)d_in[6];
    const float* sa_in_b = (const float*)d_in[7];
    const float* sa_out_w = (const float*)d_in[8];
    const float* sa_out_b = (const float*)d_in[9];
    const float* norm2_g = (const float*)d_in[10];
    const float* norm2_b = (const float*)d_in[11];
    const float* off_w = (const float*)d_in[12];
    const float* off_b = (const float*)d_in[13];
    const float* aw_w = (const float*)d_in[14];
    const float* aw_b = (const float*)d_in[15];
    const float* val_w = (const float*)d_in[16];
    const float* val_b = (const float*)d_in[17];
    const float* outp_w = (const float*)d_in[18];
    const float* outp_b = (const float*)d_in[19];
    const float* norm1_g = (const float*)d_in[20];
    const float* norm1_b = (const float*)d_in[21];
    const float* ffn_w1 = (const float*)d_in[22];
    const float* ffn_b1 = (const float*)d_in[23];
    const float* ffn_w2 = (const float*)d_in[24];
    const float* ffn_b2 = (const float*)d_in[25];
    const float* norm3_g = (const float*)d_in[26];
    const float* norm3_b = (const float*)d_in[27];
    float* outp = (float*)d_out;

    const size_t NTOK = (size_t)NB * LQ;          // 8000
    const size_t NE = NTOK * D;                   // 2,048,000
    float* w = (float*)d_ws;
    size_t off = 0;
    auto alloc = [&](size_t n) { float* p = w + off; off += n; return p; };
    float* bufA = alloc(NE);          // att -> dout
    float* bufB = alloc(NE);          // q -> sap -> ca
    float* bufC = alloc(NE);          // k -> ff
    float* bufD = alloc(NE);          // v -> offs
    float* tgt2 = alloc(NE);
    float* tgt3 = alloc(NE);
    float* awb = alloc(NTOK * 128);
    bf16* mid = (bf16*)alloc(NTOK * DFFN / 2);   // FFN mid, bf16
    bf16* value = (bf16*)(w + off);   // (NB*LEN_IN, D) bf16

    const int M8K = (int)NTOK;                    // 8000
    dim3 gD(2, (M8K + 127) / 128);                // N=256 GEMMs on 8000 rows

    // ---- self attention ----
    mfma_gemm<float, float><<<gD, 256, 0, stream>>>(tgt, qpos, sa_in_w, sa_in_b, bufB, M8K, D, D, 0);               // Q
    mfma_gemm<float, float><<<gD, 256, 0, stream>>>(tgt, qpos, sa_in_w + 256 * 256, sa_in_b + 256, bufC, M8K, D, D, 0); // K
    mfma_gemm<float, float><<<gD, 256, 0, stream>>>(tgt, nullptr, sa_in_w + 512 * 256, sa_in_b + 512, bufD, M8K, D, D, 0); // V
    attn_kernel<<<dim3((LQ + 31) / 32, NH, NB), 256, 0, stream>>>(bufB, bufC, bufD, bufA);                          // att
    mfma_gemm<float, float><<<gD, 256, 0, stream>>>(bufA, nullptr, sa_out_w, sa_out_b, bufB, M8K, D, D, 0);         // sap
    ln_res_kernel<<<NTOK, 256, 0, stream>>>(tgt, bufB, norm2_g, norm2_b, tgt2);

    // ---- deformable attention ----
    mfma_gemm<float, bf16><<<dim3(2, (NB * LEN_IN) / 128), 256, 0, stream>>>(src, nullptr, val_w, val_b, value,
                                                                             NB * LEN_IN, D, D, 0);
    mfma_gemm<float, float><<<gD, 256, 0, stream>>>(tgt2, qpos, off_w, off_b, bufD, M8K, D, D, 0);                  // offsets
    mfma_gemm<float, float><<<dim3(1, (M8K + 127) / 128), 256, 0, stream>>>(tgt2, qpos, aw_w, aw_b, awb, M8K, 128, D, 0);
    aw_softmax_kernel<<<(int)(NTOK * NH + 255) / 256, 256, 0, stream>>>(awb, (int)(NTOK * NH));
    deform_kernel<<<dim3(LQ, NH, NB), 64, 0, stream>>>(value, bufD, awb, refp, bufA);                               // dout
    mfma_gemm<float, float><<<gD, 256, 0, stream>>>(bufA, nullptr, outp_w, outp_b, bufB, M8K, D, D, 0);             // ca
    ln_res_kernel<<<NTOK, 256, 0, stream>>>(tgt2, bufB, norm1_g, norm1_b, tgt3);

    // ---- FFN ----
    mfma_gemm<float, bf16><<<dim3(DFFN / 128, (M8K + 127) / 128), 256, 0, stream>>>(tgt3, nullptr, ffn_w1, ffn_b1,
                                                                                    mid, M8K, DFFN, D, 1);
    mfma_gemm<bf16, float><<<gD, 256, 0, stream>>>(mid, nullptr, ffn_w2, ffn_b2, bufC, M8K, D, DFFN, 0);            // ff
    ln_res_kernel<<<NTOK, 256, 0, stream>>>(tgt3, bufC, norm3_g, norm3_b, outp);
}

// Round 5
// 843.232 us; speedup vs baseline: 14.1856x; 1.3876x over previous
//
#include <hip/hip_runtime.h>
#include <hip/hip_bf16.h>

#define D 256
#define NH 8
#define DH 32
#define NL 4
#define NP 4
#define DFFN 1024
#define LEN_IN 21760
#define NB 8
#define LQ 1000

typedef __hip_bfloat16 bf16;
typedef __attribute__((ext_vector_type(8))) short s8v;
typedef __attribute__((ext_vector_type(4))) float f4v;

__device__ inline float toF(float x) { return x; }
__device__ inline float toF(bf16 x) { return __bfloat162float(x); }

template <typename T> __device__ inline T fromF(float x);
template <> __device__ inline float fromF<float>(float x) { return x; }
template <> __device__ inline bf16 fromF<bf16>(float x) { return __float2bfloat16(x); }

// fp32 -> bf16 round-to-nearest-even, branchless (finite inputs)
__device__ inline short bfr(float f) {
    unsigned u = __float_as_uint(f);
    u += 0x7fff + ((u >> 16) & 1);
    return (short)(u >> 16);
}
__device__ inline s8v pack8(float4 x, float4 y) {
    s8v r;
    r[0] = bfr(x.x); r[1] = bfr(x.y); r[2] = bfr(x.z); r[3] = bfr(x.w);
    r[4] = bfr(y.x); r[5] = bfr(y.y); r[6] = bfr(y.z); r[7] = bfr(y.w);
    return r;
}

// ---------------- MFMA GEMM: C[M,N] = (A(+A2))[M,K] @ W[N,K]^T + bias, optional relu ----
template <typename TA, typename TC>
__global__ __launch_bounds__(256) void mfma_gemm(const TA* __restrict__ A, const float* __restrict__ A2,
                                                 const float* __restrict__ W, const float* __restrict__ bias,
                                                 TC* __restrict__ C, int M, int N, int K, int do_relu) {
    constexpr int LDT = 40;
    __shared__ bf16 As[128 * LDT];
    __shared__ bf16 Bs[128 * LDT];
    const int tid = threadIdx.x;
    const int m0 = blockIdx.y * 128, n0 = blockIdx.x * 128;
    const int srow = tid >> 1;
    const int sks = (tid & 1) * 16;
    const int lane = tid & 63;
    const int wave = tid >> 6;
    const int wm = (wave >> 1) * 64, wn = (wave & 1) * 64;
    const int fr = lane & 15, fq = lane >> 4;

    int arow = m0 + srow; if (arow >= M) arow = M - 1;
    const TA* aptr = A + (size_t)arow * K + sks;
    const float* a2ptr = A2 ? (A2 + (size_t)arow * K + sks) : nullptr;
    const float* wptr = W + (size_t)(n0 + srow) * K + sks;

    f4v acc[4][4];
#pragma unroll
    for (int i = 0; i < 4; ++i)
#pragma unroll
        for (int j = 0; j < 4; ++j) acc[i][j] = (f4v){0.f, 0.f, 0.f, 0.f};

    for (int k0 = 0; k0 < K; k0 += 32) {
        s8v av0, av1, wv0, wv1;
        if constexpr (sizeof(TA) == 2) {
            av0 = *(const s8v*)((const bf16*)aptr + k0);
            av1 = *(const s8v*)((const bf16*)aptr + k0 + 8);
        } else {
            float4 a0 = *(const float4*)(aptr + k0);
            float4 a1 = *(const float4*)(aptr + k0 + 4);
            float4 a2 = *(const float4*)(aptr + k0 + 8);
            float4 a3 = *(const float4*)(aptr + k0 + 12);
            if (a2ptr) {
                float4 b0 = *(const float4*)(a2ptr + k0);
                float4 b1 = *(const float4*)(a2ptr + k0 + 4);
                float4 b2 = *(const float4*)(a2ptr + k0 + 8);
                float4 b3 = *(const float4*)(a2ptr + k0 + 12);
                a0.x += b0.x; a0.y += b0.y; a0.z += b0.z; a0.w += b0.w;
                a1.x += b1.x; a1.y += b1.y; a1.z += b1.z; a1.w += b1.w;
                a2.x += b2.x; a2.y += b2.y; a2.z += b2.z; a2.w += b2.w;
                a3.x += b3.x; a3.y += b3.y; a3.z += b3.z; a3.w += b3.w;
            }
            av0 = pack8(a0, a1);
            av1 = pack8(a2, a3);
        }
        {
            float4 w0 = *(const float4*)(wptr + k0);
            float4 w1 = *(const float4*)(wptr + k0 + 4);
            float4 w2 = *(const float4*)(wptr + k0 + 8);
            float4 w3 = *(const float4*)(wptr + k0 + 12);
            wv0 = pack8(w0, w1);
            wv1 = pack8(w2, w3);
        }
        __syncthreads();
        *(s8v*)&As[srow * LDT + sks] = av0;
        *(s8v*)&As[srow * LDT + sks + 8] = av1;
        *(s8v*)&Bs[srow * LDT + sks] = wv0;
        *(s8v*)&Bs[srow * LDT + sks + 8] = wv1;
        __syncthreads();
        s8v af[4], bfv[4];
#pragma unroll
        for (int i = 0; i < 4; ++i) af[i] = *(s8v*)&As[(wm + i * 16 + fr) * LDT + fq * 8];
#pragma unroll
        for (int j = 0; j < 4; ++j) bfv[j] = *(s8v*)&Bs[(wn + j * 16 + fr) * LDT + fq * 8];
#pragma unroll
        for (int i = 0; i < 4; ++i)
#pragma unroll
            for (int j = 0; j < 4; ++j)
                acc[i][j] = __builtin_amdgcn_mfma_f32_16x16x32_bf16(af[i], bfv[j], acc[i][j], 0, 0, 0);
    }

#pragma unroll
    for (int i = 0; i < 4; ++i) {
        int rbase = m0 + wm + i * 16 + fq * 4;
#pragma unroll
        for (int r = 0; r < 4; ++r) {
            int row = rbase + r;
            if (row < M) {
#pragma unroll
                for (int j = 0; j < 4; ++j) {
                    int col = n0 + wn + j * 16 + fr;
                    float v = acc[i][j][r] + bias[col];
                    if (do_relu) v = fmaxf(v, 0.f);
                    C[(size_t)row * N + col] = fromF<TC>(v);
                }
            }
        }
    }
}

// ---------------- MFMA flash self-attention ----------------
// grid (ceil(LQ/64), NH, NB), block 256 = 4 waves; wave w owns queries q0+w*16..+15.
// Per 32-key tile: block stages K[32][32] and V^T[32][32] (bf16, stride 40);
// each wave: 2 MFMA (S) -> online softmax in C-layout -> P via LDS transpose
// (wave-private) -> 2 MFMA (PV) with alpha rescale.
__global__ __launch_bounds__(256) void attn_mfma(const float* __restrict__ q, const float* __restrict__ k,
                                                 const float* __restrict__ v, float* __restrict__ out) {
    const int h = blockIdx.y, n = blockIdx.z;
    const int tid = threadIdx.x, wave = tid >> 6, lane = tid & 63;
    const int fr = lane & 15, fq = lane >> 4;
    __shared__ short Ks[32 * 40];
    __shared__ short Vt[32 * 40];
    __shared__ short Pl[4][16 * 40];
    const int q0 = blockIdx.x * 64 + wave * 16;

    // Q A-frag: frag[e] = Q[q0+fr][fq*8+e] * scale
    s8v qfrag;
    {
        int qr = q0 + fr; if (qr >= LQ) qr = LQ - 1;
        const float* qp = q + ((size_t)(n * LQ + qr)) * D + h * DH + fq * 8;
        float4 t0 = *(const float4*)qp;
        float4 t1 = *(const float4*)(qp + 4);
        const float sc = 0.17677669529663687f;
        t0.x *= sc; t0.y *= sc; t0.z *= sc; t0.w *= sc;
        t1.x *= sc; t1.y *= sc; t1.z *= sc; t1.w *= sc;
        qfrag = pack8(t0, t1);
    }

    f4v O0 = {0.f, 0.f, 0.f, 0.f}, O1 = {0.f, 0.f, 0.f, 0.f};
    float mrow[4] = {-1e30f, -1e30f, -1e30f, -1e30f};
    float lrow[4] = {0.f, 0.f, 0.f, 0.f};

    for (int kt = 0; kt < LQ; kt += 32) {
        __syncthreads();
        {   // stage K tile: Ks[key*40 + d]
            int key = tid >> 3, d4 = (tid & 7) * 4;
            int gk = kt + key; if (gk >= LQ) gk = LQ - 1;
            const float* kp = k + ((size_t)(n * LQ + gk)) * D + h * DH + d4;
            float4 t = *(const float4*)kp;
            short4 pk; pk.x = bfr(t.x); pk.y = bfr(t.y); pk.z = bfr(t.z); pk.w = bfr(t.w);
            *(short4*)&Ks[key * 40 + d4] = pk;
        }
        {   // stage V transposed: Vt[d*40 + key]
            int d = tid & 31, key0 = (tid >> 5) * 4;
            float vv[4];
#pragma unroll
            for (int i = 0; i < 4; ++i) {
                int gk = kt + key0 + i; if (gk >= LQ) gk = LQ - 1;
                vv[i] = v[((size_t)(n * LQ + gk)) * D + h * DH + d];
            }
            short4 pk; pk.x = bfr(vv[0]); pk.y = bfr(vv[1]); pk.z = bfr(vv[2]); pk.w = bfr(vv[3]);
            *(short4*)&Vt[d * 40 + key0] = pk;
        }
        __syncthreads();

        // S = Q K^T (two 16-key subtiles). B-frag[e] = K[kt + n_local][fq*8+e]
        f4v s0 = {0.f, 0.f, 0.f, 0.f}, s1 = {0.f, 0.f, 0.f, 0.f};
        s8v kf0 = *(s8v*)&Ks[fr * 40 + fq * 8];
        s8v kf1 = *(s8v*)&Ks[(16 + fr) * 40 + fq * 8];
        s0 = __builtin_amdgcn_mfma_f32_16x16x32_bf16(qfrag, kf0, s0, 0, 0, 0);
        s1 = __builtin_amdgcn_mfma_f32_16x16x32_bf16(qfrag, kf1, s1, 0, 0, 0);
        const bool val0 = (kt + fr) < LQ, val1 = (kt + 16 + fr) < LQ;

        float p0[4], p1[4], alpha[4];
#pragma unroll
        for (int r = 0; r < 4; ++r) {
            float a = val0 ? s0[r] : -1e30f;
            float b = val1 ? s1[r] : -1e30f;
            float mx = fmaxf(a, b);
            mx = fmaxf(mx, __shfl_xor(mx, 1, 64));
            mx = fmaxf(mx, __shfl_xor(mx, 2, 64));
            mx = fmaxf(mx, __shfl_xor(mx, 4, 64));
            mx = fmaxf(mx, __shfl_xor(mx, 8, 64));
            float mnew = fmaxf(mrow[r], mx);
            float al = __expf(mrow[r] - mnew);
            float e0 = __expf(a - mnew);
            float e1 = __expf(b - mnew);
            float ps = e0 + e1;
            ps += __shfl_xor(ps, 1, 64);
            ps += __shfl_xor(ps, 2, 64);
            ps += __shfl_xor(ps, 4, 64);
            ps += __shfl_xor(ps, 8, 64);
            lrow[r] = lrow[r] * al + ps;
            mrow[r] = mnew;
            alpha[r] = al;
            p0[r] = e0; p1[r] = e1;
        }

        // P: C-layout -> LDS -> A-layout (wave-private region; DS ops in-order per wave)
        short* pw = Pl[wave];
#pragma unroll
        for (int r = 0; r < 4; ++r) {
            pw[(fq * 4 + r) * 40 + fr] = bfr(p0[r]);
            pw[(fq * 4 + r) * 40 + 16 + fr] = bfr(p1[r]);
        }
        __builtin_amdgcn_s_waitcnt(0);   // belt-and-braces: writes visible before frag read
        s8v pfrag = *(s8v*)&pw[fr * 40 + fq * 8];
        s8v vf0 = *(s8v*)&Vt[fr * 40 + fq * 8];          // d = fr
        s8v vf1 = *(s8v*)&Vt[(16 + fr) * 40 + fq * 8];   // d = 16+fr
#pragma unroll
        for (int r = 0; r < 4; ++r) { O0[r] *= alpha[r]; O1[r] *= alpha[r]; }
        O0 = __builtin_amdgcn_mfma_f32_16x16x32_bf16(pfrag, vf0, O0, 0, 0, 0);
        O1 = __builtin_amdgcn_mfma_f32_16x16x32_bf16(pfrag, vf1, O1, 0, 0, 0);
    }

#pragma unroll
    for (int r = 0; r < 4; ++r) {
        int qrow = q0 + fq * 4 + r;
        if (qrow < LQ) {
            float inv = 1.0f / lrow[r];
            float* op = out + ((size_t)(n * LQ + qrow)) * D + h * DH;
            op[fr] = O0[r] * inv;
            op[16 + fr] = O1[r] * inv;
        }
    }
}

// ---------------- residual + layernorm ----------------
__global__ __launch_bounds__(256) void ln_res_kernel(const float* __restrict__ base, const float* __restrict__ delta,
                                                     const float* __restrict__ g, const float* __restrict__ b,
                                                     float* __restrict__ out) {
    __shared__ float scratch[8];
    const size_t row = blockIdx.x;
    const int d = threadIdx.x;
    float x = base[row * D + d] + delta[row * D + d];
    float s1 = x, s2 = x * x;
    for (int o = 32; o > 0; o >>= 1) {
        s1 += __shfl_down(s1, o, 64);
        s2 += __shfl_down(s2, o, 64);
    }
    const int w = threadIdx.x >> 6, lane = threadIdx.x & 63;
    if (lane == 0) { scratch[w] = s1; scratch[4 + w] = s2; }
    __syncthreads();
    s1 = scratch[0] + scratch[1] + scratch[2] + scratch[3];
    s2 = scratch[4] + scratch[5] + scratch[6] + scratch[7];
    float mean = s1 * (1.0f / 256.0f);
    float var = s2 * (1.0f / 256.0f) - mean * mean;
    float rstd = rsqrtf(var + 1e-5f);
    float y = (x - mean) * rstd * g[d] + b[d];
    out[row * D + d] = y;
}

// ---------------- softmax over 16 (NL*NP) ----------------
__global__ __launch_bounds__(256) void aw_softmax_kernel(float* __restrict__ aw, int ngrp) {
    int t = blockIdx.x * 256 + threadIdx.x;
    if (t >= ngrp) return;
    float* p = aw + (size_t)t * 16;
    float m = p[0];
#pragma unroll
    for (int i = 1; i < 16; ++i) m = fmaxf(m, p[i]);
    float s = 0.f;
    float e[16];
#pragma unroll
    for (int i = 0; i < 16; ++i) { e[i] = __expf(p[i] - m); s += e[i]; }
    float inv = 1.0f / s;
#pragma unroll
    for (int i = 0; i < 16; ++i) p[i] = e[i] * inv;
}

// ---------------- MS-deformable bilinear sampling ----------------
__global__ __launch_bounds__(64) void deform_kernel(const bf16* __restrict__ value, const float* __restrict__ offs,
                                                    const float* __restrict__ aw, const float* __restrict__ refp,
                                                    float* __restrict__ out) {
    const int qi = blockIdx.x, h = blockIdx.y, n = blockIdx.z;
    const int d = threadIdx.x & 31, half = threadIdx.x >> 5;
    const size_t row = (size_t)n * LQ + qi;
    const int HL[4] = {128, 64, 32, 16};
    const int WL[4] = {128, 64, 32, 16};
    const int START[4] = {0, 16384, 20480, 21504};
    float acc = 0.f;
    for (int lp = half * 8; lp < half * 8 + 8; ++lp) {
        int l = lp >> 2, p = lp & 3;
        int W = WL[l], H = HL[l];
        float rx = refp[(row * NL + l) * 2 + 0];
        float ry = refp[(row * NL + l) * 2 + 1];
        float ox = offs[row * D + ((h * NL + l) * NP + p) * 2 + 0];
        float oy = offs[row * D + ((h * NL + l) * NP + p) * 2 + 1];
        float w_attn = aw[row * 128 + h * 16 + lp];
        float x = (rx + ox / W) * W - 0.5f;
        float y = (ry + oy / H) * H - 0.5f;
        float x0 = floorf(x), y0 = floorf(y);
        float lx = x - x0, ly = y - y0;
        int x0i = (int)x0, y0i = (int)y0;
        float sample = 0.f;
#pragma unroll
        for (int c = 0; c < 4; ++c) {
            int dy = c >> 1, dx = c & 1;
            int xi = x0i + dx, yi = y0i + dy;
            if (xi >= 0 && xi < W && yi >= 0 && yi < H) {
                float wgt = (dy ? ly : 1.f - ly) * (dx ? lx : 1.f - lx);
                size_t vrow = (size_t)n * LEN_IN + START[l] + yi * W + xi;
                sample += wgt * toF(value[vrow * D + h * DH + d]);
            }
        }
        acc += w_attn * sample;
    }
    acc += __shfl_down(acc, 32, 64);
    if (half == 0) out[row * D + h * DH + d] = acc;
}

// ---------------- host ----------------
extern "C" void kernel_launch(void* const* d_in, const int* in_sizes, int n_in,
                              void* d_out, int out_size, void* d_ws, size_t ws_size,
                              hipStream_t stream) {
    const float* tgt = (const float*)d_in[0];
    const float* qpos = (const float*)d_in[1];
    const float* refp = (const float*)d_in[2];
    const float* src = (const float*)d_in[3];
    const float* sa_in_w = (const float*)d_in[6];
    const float* sa_in_b = (const float*)d_in[7];
    const float* sa_out_w = (const float*)d_in[8];
    const float* sa_out_b = (const float*)d_in[9];
    const float* norm2_g = (const float*)d_in[10];
    const float* norm2_b = (const float*)d_in[11];
    const float* off_w = (const float*)d_in[12];
    const float* off_b = (const float*)d_in[13];
    const float* aw_w = (const float*)d_in[14];
    const float* aw_b = (const float*)d_in[15];
    const float* val_w = (const float*)d_in[16];
    const float* val_b = (const float*)d_in[17];
    const float* outp_w = (const float*)d_in[18];
    const float* outp_b = (const float*)d_in[19];
    const float* norm1_g = (const float*)d_in[20];
    const float* norm1_b = (const float*)d_in[21];
    const float* ffn_w1 = (const float*)d_in[22];
    const float* ffn_b1 = (const float*)d_in[23];
    const float* ffn_w2 = (const float*)d_in[24];
    const float* ffn_b2 = (const float*)d_in[25];
    const float* norm3_g = (const float*)d_in[26];
    const float* norm3_b = (const float*)d_in[27];
    float* outp = (float*)d_out;

    const size_t NTOK = (size_t)NB * LQ;          // 8000
    const size_t NE = NTOK * D;                   // 2,048,000
    float* w = (float*)d_ws;
    size_t off = 0;
    auto alloc = [&](size_t n) { float* p = w + off; off += n; return p; };
    float* bufA = alloc(NE);          // att -> dout
    float* bufB = alloc(NE);          // q -> sap -> ca
    float* bufC = alloc(NE);          // k -> ff
    float* bufD = alloc(NE);          // v -> offs
    float* tgt2 = alloc(NE);
    float* tgt3 = alloc(NE);
    float* awb = alloc(NTOK * 128);
    bf16* mid = (bf16*)alloc(NTOK * DFFN / 2);   // FFN mid, bf16
    bf16* value = (bf16*)(w + off);   // (NB*LEN_IN, D) bf16

    const int M8K = (int)NTOK;                    // 8000
    dim3 gD(2, (M8K + 127) / 128);                // N=256 GEMMs on 8000 rows

    // ---- self attention ----
    mfma_gemm<float, float><<<gD, 256, 0, stream>>>(tgt, qpos, sa_in_w, sa_in_b, bufB, M8K, D, D, 0);               // Q
    mfma_gemm<float, float><<<gD, 256, 0, stream>>>(tgt, qpos, sa_in_w + 256 * 256, sa_in_b + 256, bufC, M8K, D, D, 0); // K
    mfma_gemm<float, float><<<gD, 256, 0, stream>>>(tgt, nullptr, sa_in_w + 512 * 256, sa_in_b + 512, bufD, M8K, D, D, 0); // V
    attn_mfma<<<dim3((LQ + 63) / 64, NH, NB), 256, 0, stream>>>(bufB, bufC, bufD, bufA);                            // att
    mfma_gemm<float, float><<<gD, 256, 0, stream>>>(bufA, nullptr, sa_out_w, sa_out_b, bufB, M8K, D, D, 0);         // sap
    ln_res_kernel<<<NTOK, 256, 0, stream>>>(tgt, bufB, norm2_g, norm2_b, tgt2);

    // ---- deformable attention ----
    mfma_gemm<float, bf16><<<dim3(2, (NB * LEN_IN) / 128), 256, 0, stream>>>(src, nullptr, val_w, val_b, value,
                                                                             NB * LEN_IN, D, D, 0);
    mfma_gemm<float, float><<<gD, 256, 0, stream>>>(tgt2, qpos, off_w, off_b, bufD, M8K, D, D, 0);                  // offsets
    mfma_gemm<float, float><<<dim3(1, (M8K + 127) / 128), 256, 0, stream>>>(tgt2, qpos, aw_w, aw_b, awb, M8K, 128, D, 0);
    aw_softmax_kernel<<<(int)(NTOK * NH + 255) / 256, 256, 0, stream>>>(awb, (int)(NTOK * NH));
    deform_kernel<<<dim3(LQ, NH, NB), 64, 0, stream>>>(value, bufD, awb, refp, bufA);                               // dout
    mfma_gemm<float, float><<<gD, 256, 0, stream>>>(bufA, nullptr, outp_w, outp_b, bufB, M8K, D, D, 0);             // ca
    ln_res_kernel<<<NTOK, 256, 0, stream>>>(tgt2, bufB, norm1_g, norm1_b, tgt3);

    // ---- FFN ----
    mfma_gemm<float, bf16><<<dim3(DFFN / 128, (M8K + 127) / 128), 256, 0, stream>>>(tgt3, nullptr, ffn_w1, ffn_b1,
                                                                                    mid, M8K, DFFN, D, 1);
    mfma_gemm<bf16, float><<<gD, 256, 0, stream>>>(mid, nullptr, ffn_w2, ffn_b2, bufC, M8K, D, DFFN, 0);            // ff
    ln_res_kernel<<<NTOK, 256, 0, stream>>>(tgt3, bufC, norm3_g, norm3_b, outp);
}

// Round 6
// 692.779 us; speedup vs baseline: 17.2663x; 1.2172x over previous
//
#include <hip/hip_runtime.h>
#include <hip/hip_bf16.h>

#define D 256
#define NH 8
#define DH 32
#define NL 4
#define NP 4
#define DFFN 1024
#define LEN_IN 21760
#define NB 8
#define LQ 1000

typedef __hip_bfloat16 bf16;
typedef __attribute__((ext_vector_type(8))) short s8v;
typedef __attribute__((ext_vector_type(4))) float f4v;

__device__ inline float toF(float x) { return x; }
__device__ inline float toF(bf16 x) { return __bfloat162float(x); }

template <typename T> __device__ inline T fromF(float x);
template <> __device__ inline float fromF<float>(float x) { return x; }
template <> __device__ inline bf16 fromF<bf16>(float x) { return __float2bfloat16(x); }

// fp32 -> bf16 round-to-nearest-even, branchless (finite inputs)
__device__ inline short bfr(float f) {
    unsigned u = __float_as_uint(f);
    u += 0x7fff + ((u >> 16) & 1);
    return (short)(u >> 16);
}
__device__ inline s8v pack8(float4 x, float4 y) {
    s8v r;
    r[0] = bfr(x.x); r[1] = bfr(x.y); r[2] = bfr(x.z); r[3] = bfr(x.w);
    r[4] = bfr(y.x); r[5] = bfr(y.y); r[6] = bfr(y.z); r[7] = bfr(y.w);
    return r;
}

// ---------------- MFMA GEMM: C[M,N] = (A(+A2))[M,K] @ W[N,K]^T + bias, optional relu ----
template <typename TA, typename TC>
__global__ __launch_bounds__(256) void mfma_gemm(const TA* __restrict__ A, const float* __restrict__ A2,
                                                 const float* __restrict__ W, const float* __restrict__ bias,
                                                 TC* __restrict__ C, int M, int N, int K, int do_relu) {
    constexpr int LDT = 40;
    __shared__ bf16 As[128 * LDT];
    __shared__ bf16 Bs[128 * LDT];
    const int tid = threadIdx.x;
    const int m0 = blockIdx.y * 128, n0 = blockIdx.x * 128;
    const int srow = tid >> 1;
    const int sks = (tid & 1) * 16;
    const int lane = tid & 63;
    const int wave = tid >> 6;
    const int wm = (wave >> 1) * 64, wn = (wave & 1) * 64;
    const int fr = lane & 15, fq = lane >> 4;

    int arow = m0 + srow; if (arow >= M) arow = M - 1;
    const TA* aptr = A + (size_t)arow * K + sks;
    const float* a2ptr = A2 ? (A2 + (size_t)arow * K + sks) : nullptr;
    const float* wptr = W + (size_t)(n0 + srow) * K + sks;

    f4v acc[4][4];
#pragma unroll
    for (int i = 0; i < 4; ++i)
#pragma unroll
        for (int j = 0; j < 4; ++j) acc[i][j] = (f4v){0.f, 0.f, 0.f, 0.f};

    for (int k0 = 0; k0 < K; k0 += 32) {
        s8v av0, av1, wv0, wv1;
        if constexpr (sizeof(TA) == 2) {
            av0 = *(const s8v*)((const bf16*)aptr + k0);
            av1 = *(const s8v*)((const bf16*)aptr + k0 + 8);
        } else {
            float4 a0 = *(const float4*)(aptr + k0);
            float4 a1 = *(const float4*)(aptr + k0 + 4);
            float4 a2 = *(const float4*)(aptr + k0 + 8);
            float4 a3 = *(const float4*)(aptr + k0 + 12);
            if (a2ptr) {
                float4 b0 = *(const float4*)(a2ptr + k0);
                float4 b1 = *(const float4*)(a2ptr + k0 + 4);
                float4 b2 = *(const float4*)(a2ptr + k0 + 8);
                float4 b3 = *(const float4*)(a2ptr + k0 + 12);
                a0.x += b0.x; a0.y += b0.y; a0.z += b0.z; a0.w += b0.w;
                a1.x += b1.x; a1.y += b1.y; a1.z += b1.z; a1.w += b1.w;
                a2.x += b2.x; a2.y += b2.y; a2.z += b2.z; a2.w += b2.w;
                a3.x += b3.x; a3.y += b3.y; a3.z += b3.z; a3.w += b3.w;
            }
            av0 = pack8(a0, a1);
            av1 = pack8(a2, a3);
        }
        {
            float4 w0 = *(const float4*)(wptr + k0);
            float4 w1 = *(const float4*)(wptr + k0 + 4);
            float4 w2 = *(const float4*)(wptr + k0 + 8);
            float4 w3 = *(const float4*)(wptr + k0 + 12);
            wv0 = pack8(w0, w1);
            wv1 = pack8(w2, w3);
        }
        __syncthreads();
        *(s8v*)&As[srow * LDT + sks] = av0;
        *(s8v*)&As[srow * LDT + sks + 8] = av1;
        *(s8v*)&Bs[srow * LDT + sks] = wv0;
        *(s8v*)&Bs[srow * LDT + sks + 8] = wv1;
        __syncthreads();
        s8v af[4], bfv[4];
#pragma unroll
        for (int i = 0; i < 4; ++i) af[i] = *(s8v*)&As[(wm + i * 16 + fr) * LDT + fq * 8];
#pragma unroll
        for (int j = 0; j < 4; ++j) bfv[j] = *(s8v*)&Bs[(wn + j * 16 + fr) * LDT + fq * 8];
#pragma unroll
        for (int i = 0; i < 4; ++i)
#pragma unroll
            for (int j = 0; j < 4; ++j)
                acc[i][j] = __builtin_amdgcn_mfma_f32_16x16x32_bf16(af[i], bfv[j], acc[i][j], 0, 0, 0);
    }

#pragma unroll
    for (int i = 0; i < 4; ++i) {
        int rbase = m0 + wm + i * 16 + fq * 4;
#pragma unroll
        for (int r = 0; r < 4; ++r) {
            int row = rbase + r;
            if (row < M) {
#pragma unroll
                for (int j = 0; j < 4; ++j) {
                    int col = n0 + wn + j * 16 + fr;
                    float v = acc[i][j][r] + bias[col];
                    if (do_relu) v = fmaxf(v, 0.f);
                    C[(size_t)row * N + col] = fromF<TC>(v);
                }
            }
        }
    }
}

// ---------------- MFMA flash self-attention ----------------
__global__ __launch_bounds__(256) void attn_mfma(const float* __restrict__ q, const float* __restrict__ k,
                                                 const float* __restrict__ v, float* __restrict__ out) {
    const int h = blockIdx.y, n = blockIdx.z;
    const int tid = threadIdx.x, wave = tid >> 6, lane = tid & 63;
    const int fr = lane & 15, fq = lane >> 4;
    __shared__ short Ks[32 * 40];
    __shared__ short Vt[32 * 40];
    __shared__ short Pl[4][16 * 40];
    const int q0 = blockIdx.x * 64 + wave * 16;

    s8v qfrag;
    {
        int qr = q0 + fr; if (qr >= LQ) qr = LQ - 1;
        const float* qp = q + ((size_t)(n * LQ + qr)) * D + h * DH + fq * 8;
        float4 t0 = *(const float4*)qp;
        float4 t1 = *(const float4*)(qp + 4);
        const float sc = 0.17677669529663687f;
        t0.x *= sc; t0.y *= sc; t0.z *= sc; t0.w *= sc;
        t1.x *= sc; t1.y *= sc; t1.z *= sc; t1.w *= sc;
        qfrag = pack8(t0, t1);
    }

    f4v O0 = {0.f, 0.f, 0.f, 0.f}, O1 = {0.f, 0.f, 0.f, 0.f};
    float mrow[4] = {-1e30f, -1e30f, -1e30f, -1e30f};
    float lrow[4] = {0.f, 0.f, 0.f, 0.f};

    for (int kt = 0; kt < LQ; kt += 32) {
        __syncthreads();
        {
            int key = tid >> 3, d4 = (tid & 7) * 4;
            int gk = kt + key; if (gk >= LQ) gk = LQ - 1;
            const float* kp = k + ((size_t)(n * LQ + gk)) * D + h * DH + d4;
            float4 t = *(const float4*)kp;
            short4 pk; pk.x = bfr(t.x); pk.y = bfr(t.y); pk.z = bfr(t.z); pk.w = bfr(t.w);
            *(short4*)&Ks[key * 40 + d4] = pk;
        }
        {
            int d = tid & 31, key0 = (tid >> 5) * 4;
            float vv[4];
#pragma unroll
            for (int i = 0; i < 4; ++i) {
                int gk = kt + key0 + i; if (gk >= LQ) gk = LQ - 1;
                vv[i] = v[((size_t)(n * LQ + gk)) * D + h * DH + d];
            }
            short4 pk; pk.x = bfr(vv[0]); pk.y = bfr(vv[1]); pk.z = bfr(vv[2]); pk.w = bfr(vv[3]);
            *(short4*)&Vt[d * 40 + key0] = pk;
        }
        __syncthreads();

        f4v s0 = {0.f, 0.f, 0.f, 0.f}, s1 = {0.f, 0.f, 0.f, 0.f};
        s8v kf0 = *(s8v*)&Ks[fr * 40 + fq * 8];
        s8v kf1 = *(s8v*)&Ks[(16 + fr) * 40 + fq * 8];
        s0 = __builtin_amdgcn_mfma_f32_16x16x32_bf16(qfrag, kf0, s0, 0, 0, 0);
        s1 = __builtin_amdgcn_mfma_f32_16x16x32_bf16(qfrag, kf1, s1, 0, 0, 0);
        const bool val0 = (kt + fr) < LQ, val1 = (kt + 16 + fr) < LQ;

        float p0[4], p1[4], alpha[4];
#pragma unroll
        for (int r = 0; r < 4; ++r) {
            float a = val0 ? s0[r] : -1e30f;
            float b = val1 ? s1[r] : -1e30f;
            float mx = fmaxf(a, b);
            mx = fmaxf(mx, __shfl_xor(mx, 1, 64));
            mx = fmaxf(mx, __shfl_xor(mx, 2, 64));
            mx = fmaxf(mx, __shfl_xor(mx, 4, 64));
            mx = fmaxf(mx, __shfl_xor(mx, 8, 64));
            float mnew = fmaxf(mrow[r], mx);
            float al = __expf(mrow[r] - mnew);
            float e0 = __expf(a - mnew);
            float e1 = __expf(b - mnew);
            float ps = e0 + e1;
            ps += __shfl_xor(ps, 1, 64);
            ps += __shfl_xor(ps, 2, 64);
            ps += __shfl_xor(ps, 4, 64);
            ps += __shfl_xor(ps, 8, 64);
            lrow[r] = lrow[r] * al + ps;
            mrow[r] = mnew;
            alpha[r] = al;
            p0[r] = e0; p1[r] = e1;
        }

        short* pw = Pl[wave];
#pragma unroll
        for (int r = 0; r < 4; ++r) {
            pw[(fq * 4 + r) * 40 + fr] = bfr(p0[r]);
            pw[(fq * 4 + r) * 40 + 16 + fr] = bfr(p1[r]);
        }
        __builtin_amdgcn_s_waitcnt(0);
        s8v pfrag = *(s8v*)&pw[fr * 40 + fq * 8];
        s8v vf0 = *(s8v*)&Vt[fr * 40 + fq * 8];
        s8v vf1 = *(s8v*)&Vt[(16 + fr) * 40 + fq * 8];
#pragma unroll
        for (int r = 0; r < 4; ++r) { O0[r] *= alpha[r]; O1[r] *= alpha[r]; }
        O0 = __builtin_amdgcn_mfma_f32_16x16x32_bf16(pfrag, vf0, O0, 0, 0, 0);
        O1 = __builtin_amdgcn_mfma_f32_16x16x32_bf16(pfrag, vf1, O1, 0, 0, 0);
    }

#pragma unroll
    for (int r = 0; r < 4; ++r) {
        int qrow = q0 + fq * 4 + r;
        if (qrow < LQ) {
            float inv = 1.0f / lrow[r];
            float* op = out + ((size_t)(n * LQ + qrow)) * D + h * DH;
            op[fr] = O0[r] * inv;
            op[16 + fr] = O1[r] * inv;
        }
    }
}

// ---------------- residual + layernorm ----------------
__global__ __launch_bounds__(256) void ln_res_kernel(const float* __restrict__ base, const float* __restrict__ delta,
                                                     const float* __restrict__ g, const float* __restrict__ b,
                                                     float* __restrict__ out) {
    __shared__ float scratch[8];
    const size_t row = blockIdx.x;
    const int d = threadIdx.x;
    float x = base[row * D + d] + delta[row * D + d];
    float s1 = x, s2 = x * x;
    for (int o = 32; o > 0; o >>= 1) {
        s1 += __shfl_down(s1, o, 64);
        s2 += __shfl_down(s2, o, 64);
    }
    const int w = threadIdx.x >> 6, lane = threadIdx.x & 63;
    if (lane == 0) { scratch[w] = s1; scratch[4 + w] = s2; }
    __syncthreads();
    s1 = scratch[0] + scratch[1] + scratch[2] + scratch[3];
    s2 = scratch[4] + scratch[5] + scratch[6] + scratch[7];
    float mean = s1 * (1.0f / 256.0f);
    float var = s2 * (1.0f / 256.0f) - mean * mean;
    float rstd = rsqrtf(var + 1e-5f);
    float y = (x - mean) * rstd * g[d] + b[d];
    out[row * D + d] = y;
}

// ---------------- softmax over 16 (NL*NP) ----------------
__global__ __launch_bounds__(256) void aw_softmax_kernel(float* __restrict__ aw, int ngrp) {
    int t = blockIdx.x * 256 + threadIdx.x;
    if (t >= ngrp) return;
    float* p = aw + (size_t)t * 16;
    float m = p[0];
#pragma unroll
    for (int i = 1; i < 16; ++i) m = fmaxf(m, p[i]);
    float s = 0.f;
    float e[16];
#pragma unroll
    for (int i = 0; i < 16; ++i) { e[i] = __expf(p[i] - m); s += e[i]; }
    float inv = 1.0f / s;
#pragma unroll
    for (int i = 0; i < 16; ++i) p[i] = e[i] * inv;
}

// ---------------- MS-deformable bilinear sampling ----------------
// block 256 = 4 waves, wave = 1 query. lane = l*16 + c: subgroup l owns level l
// (W/H/START loop-invariant), lane c owns channels {2c, 2c+1} via one dword load.
__global__ __launch_bounds__(256) void deform_kernel(const bf16* __restrict__ value, const float* __restrict__ offs,
                                                     const float* __restrict__ aw, const float* __restrict__ refp,
                                                     float* __restrict__ out) {
    const int h = blockIdx.y, n = blockIdx.z;
    const int tid = threadIdx.x;
    const int wave = tid >> 6, lane = tid & 63;
    const int qi = blockIdx.x * 4 + wave;
    const int c = lane & 15;          // channel pair -> channels 2c, 2c+1
    const int l = lane >> 4;          // level
    const size_t row = (size_t)n * LQ + qi;
    const int W = 128 >> l, H = 128 >> l;
    const int START[4] = {0, 16384, 20480, 21504};
    const float invW = 1.0f / W, invH = 1.0f / H;

    const float rx = refp[(row * NL + l) * 2 + 0];
    const float ry = refp[(row * NL + l) * 2 + 1];
    const bf16* vbase = value + ((size_t)n * LEN_IN + START[l]) * D + h * DH + 2 * c;
    const float* offp = offs + row * D + (h * NL + l) * NP * 2;
    const float* awp = aw + row * 128 + h * 16 + l * 4;

    float acc0 = 0.f, acc1 = 0.f;
#pragma unroll
    for (int p = 0; p < 4; ++p) {
        float ox = offp[p * 2 + 0];
        float oy = offp[p * 2 + 1];
        float wa = awp[p];
        float x = (rx + ox * invW) * W - 0.5f;
        float y = (ry + oy * invH) * H - 0.5f;
        float xf = floorf(x), yf = floorf(y);
        float lx = x - xf, ly = y - yf;
        int x0 = (int)xf, y0 = (int)yf;
        int x1 = x0 + 1, y1 = y0 + 1;
        float vx0 = (x0 >= 0 && x0 < W) ? 1.f : 0.f;
        float vx1 = (x1 >= 0 && x1 < W) ? 1.f : 0.f;
        float vy0 = (y0 >= 0 && y0 < H) ? 1.f : 0.f;
        float vy1 = (y1 >= 0 && y1 < H) ? 1.f : 0.f;
        int x0c = min(max(x0, 0), W - 1), x1c = min(max(x1, 0), W - 1);
        int y0c = min(max(y0, 0), H - 1), y1c = min(max(y1, 0), H - 1);
        float w00 = wa * (1.f - ly) * (1.f - lx) * vy0 * vx0;
        float w01 = wa * (1.f - ly) * lx * vy0 * vx1;
        float w10 = wa * ly * (1.f - lx) * vy1 * vx0;
        float w11 = wa * ly * lx * vy1 * vx1;
        unsigned u00 = *(const unsigned*)(vbase + (size_t)(y0c * W + x0c) * D);
        unsigned u01 = *(const unsigned*)(vbase + (size_t)(y0c * W + x1c) * D);
        unsigned u10 = *(const unsigned*)(vbase + (size_t)(y1c * W + x0c) * D);
        unsigned u11 = *(const unsigned*)(vbase + (size_t)(y1c * W + x1c) * D);
        acc0 += w00 * __uint_as_float(u00 << 16) + w01 * __uint_as_float(u01 << 16)
              + w10 * __uint_as_float(u10 << 16) + w11 * __uint_as_float(u11 << 16);
        acc1 += w00 * __uint_as_float(u00 & 0xffff0000u) + w01 * __uint_as_float(u01 & 0xffff0000u)
              + w10 * __uint_as_float(u10 & 0xffff0000u) + w11 * __uint_as_float(u11 & 0xffff0000u);
    }
    acc0 += __shfl_xor(acc0, 16, 64); acc0 += __shfl_xor(acc0, 32, 64);
    acc1 += __shfl_xor(acc1, 16, 64); acc1 += __shfl_xor(acc1, 32, 64);
    if (l == 0) {
        float2 st = {acc0, acc1};
        *(float2*)(out + row * D + h * DH + 2 * c) = st;
    }
}

// ---------------- host ----------------
extern "C" void kernel_launch(void* const* d_in, const int* in_sizes, int n_in,
                              void* d_out, int out_size, void* d_ws, size_t ws_size,
                              hipStream_t stream) {
    const float* tgt = (const float*)d_in[0];
    const float* qpos = (const float*)d_in[1];
    const float* refp = (const float*)d_in[2];
    const float* src = (const float*)d_in[3];
    const float* sa_in_w = (const float*)d_in[6];
    const float* sa_in_b = (const float*)d_in[7];
    const float* sa_out_w = (const float*)d_in[8];
    const float* sa_out_b = (const float*)d_in[9];
    const float* norm2_g = (const float*)d_in[10];
    const float* norm2_b = (const float*)d_in[11];
    const float* off_w = (const float*)d_in[12];
    const float* off_b = (const float*)d_in[13];
    const float* aw_w = (const float*)d_in[14];
    const float* aw_b = (const float*)d_in[15];
    const float* val_w = (const float*)d_in[16];
    const float* val_b = (const float*)d_in[17];
    const float* outp_w = (const float*)d_in[18];
    const float* outp_b = (const float*)d_in[19];
    const float* norm1_g = (const float*)d_in[20];
    const float* norm1_b = (const float*)d_in[21];
    const float* ffn_w1 = (const float*)d_in[22];
    const float* ffn_b1 = (const float*)d_in[23];
    const float* ffn_w2 = (const float*)d_in[24];
    const float* ffn_b2 = (const float*)d_in[25];
    const float* norm3_g = (const float*)d_in[26];
    const float* norm3_b = (const float*)d_in[27];
    float* outp = (float*)d_out;

    const size_t NTOK = (size_t)NB * LQ;          // 8000
    const size_t NE = NTOK * D;                   // 2,048,000
    float* w = (float*)d_ws;
    size_t off = 0;
    auto alloc = [&](size_t n) { float* p = w + off; off += n; return p; };
    float* bufA = alloc(NE);          // att -> dout
    float* bufB = alloc(NE);          // q -> sap -> ca
    float* bufC = alloc(NE);          // k -> ff
    float* bufD = alloc(NE);          // v -> offs
    float* tgt2 = alloc(NE);
    float* tgt3 = alloc(NE);
    float* awb = alloc(NTOK * 128);
    bf16* mid = (bf16*)alloc(NTOK * DFFN / 2);   // FFN mid, bf16
    bf16* value = (bf16*)(w + off);   // (NB*LEN_IN, D) bf16

    const int M8K = (int)NTOK;                    // 8000
    dim3 gD(2, (M8K + 127) / 128);                // N=256 GEMMs on 8000 rows

    // ---- self attention ----
    mfma_gemm<float, float><<<gD, 256, 0, stream>>>(tgt, qpos, sa_in_w, sa_in_b, bufB, M8K, D, D, 0);               // Q
    mfma_gemm<float, float><<<gD, 256, 0, stream>>>(tgt, qpos, sa_in_w + 256 * 256, sa_in_b + 256, bufC, M8K, D, D, 0); // K
    mfma_gemm<float, float><<<gD, 256, 0, stream>>>(tgt, nullptr, sa_in_w + 512 * 256, sa_in_b + 512, bufD, M8K, D, D, 0); // V
    attn_mfma<<<dim3((LQ + 63) / 64, NH, NB), 256, 0, stream>>>(bufB, bufC, bufD, bufA);                            // att
    mfma_gemm<float, float><<<gD, 256, 0, stream>>>(bufA, nullptr, sa_out_w, sa_out_b, bufB, M8K, D, D, 0);         // sap
    ln_res_kernel<<<NTOK, 256, 0, stream>>>(tgt, bufB, norm2_g, norm2_b, tgt2);

    // ---- deformable attention ----
    mfma_gemm<float, bf16><<<dim3(2, (NB * LEN_IN) / 128), 256, 0, stream>>>(src, nullptr, val_w, val_b, value,
                                                                             NB * LEN_IN, D, D, 0);
    mfma_gemm<float, float><<<gD, 256, 0, stream>>>(tgt2, qpos, off_w, off_b, bufD, M8K, D, D, 0);                  // offsets
    mfma_gemm<float, float><<<dim3(1, (M8K + 127) / 128), 256, 0, stream>>>(tgt2, qpos, aw_w, aw_b, awb, M8K, 128, D, 0);
    aw_softmax_kernel<<<(int)(NTOK * NH + 255) / 256, 256, 0, stream>>>(awb, (int)(NTOK * NH));
    deform_kernel<<<dim3(LQ / 4, NH, NB), 256, 0, stream>>>(value, bufD, awb, refp, bufA);                          // dout
    mfma_gemm<float, float><<<gD, 256, 0, stream>>>(bufA, nullptr, outp_w, outp_b, bufB, M8K, D, D, 0);             // ca
    ln_res_kernel<<<NTOK, 256, 0, stream>>>(tgt2, bufB, norm1_g, norm1_b, tgt3);

    // ---- FFN ----
    mfma_gemm<float, bf16><<<dim3(DFFN / 128, (M8K + 127) / 128), 256, 0, stream>>>(tgt3, nullptr, ffn_w1, ffn_b1,
                                                                                    mid, M8K, DFFN, D, 1);
    mfma_gemm<bf16, float><<<gD, 256, 0, stream>>>(mid, nullptr, ffn_w2, ffn_b2, bufC, M8K, D, DFFN, 0);            // ff
    ln_res_kernel<<<NTOK, 256, 0, stream>>>(tgt3, bufC, norm3_g, norm3_b, outp);
}